// Round 11
// baseline (121.665 us; speedup 1.0000x reference)
//
#include <hip/hip_runtime.h>

// LSS voxel pooling: 996864 points x 64ch -> [B=4, C=64, X=150, Y=200] fp32.
// v11: accum gathers float4/lane (16 lanes per 256B row -> 4 rows per wave
// instruction; 4 cells/wave with independent chains -> up to 16 rows in
// flight). shfl_xor butterfly merges the 4 row-groups, LDS transpose epilogue
// unchanged. zero / bin_push / binning math (r5-validated) unchanged.

#define NPRIME 996864
#define NCH 64
#define NX0 150
#define NX1 200
#define CELLS_PER_B (NX0 * NX1)          // 30000
#define NCELLS (4 * CELLS_PER_B)         // 120000
#define BATCH_STRIDE (NPRIME / 4)        // 249216
#define CAP 44                            // max pts/cell; Poisson(6.8): P(>=44)~1e-19
#define CNT_BYTES ((size_t)NCELLS * 4)               // 480,000
#define SLOT_BYTES ((size_t)NCELLS * CAP * 4)        // 21,120,000
#define CELL_BYTES ((size_t)NPRIME * 4)              // fallback

__device__ __forceinline__ int bin_recip(float v, float off, float rcp) {
    float num = v - off;       // f32 RN subtract
    float q   = num * rcp;     // f32 RN multiply by folded reciprocal
    return (int)q;             // trunc toward zero
}

__device__ __forceinline__ int compute_cell(float gx, float gy, float gz, int p) {
    int i0 = bin_recip(gx,   0.0f, 1.0f / 0.6f);
    int i1 = bin_recip(gy, -15.0f, 1.0f / 0.15f);
    int i2 = bin_recip(gz, -10.0f, 1.0f / 20.0f);
    bool kept = (i0 >= 0) & (i0 < NX0) & (i1 >= 0) & (i1 < NX1) & (i2 >= 0) & (i2 < 1);
    int b = p / BATCH_STRIDE;
    return kept ? (b * CELLS_PER_B + i0 * NX1 + i1) : -1;
}

// k0: zero the counters.
__global__ __launch_bounds__(256) void lss_zero(unsigned* __restrict__ cnt) {
    int i = blockIdx.x * 256 + threadIdx.x;
    if (i < NCELLS) cnt[i] = 0u;
}

// k1: bin + push into per-cell slot lists.
__global__ __launch_bounds__(256) void lss_bin_push(
    const float* __restrict__ geom,      // [NPRIME, 3]
    unsigned* __restrict__ cnt,          // [NCELLS]
    int* __restrict__ slots)             // [NCELLS, CAP]
{
    int p = blockIdx.x * 256 + threadIdx.x;
    if (p >= NPRIME) return;
    float gx = geom[3 * p + 0];
    float gy = geom[3 * p + 1];
    float gz = geom[3 * p + 2];
    int c = compute_cell(gx, gy, gz, p);
    if (c < 0) return;
    unsigned pos = atomicAdd(&cnt[c], 1u);
    if (pos < CAP) slots[c * CAP + pos] = p;
}

// k2: quad-row gather reduction. Block = 1024 thr (16 waves) covers 64 cells;
// each wave owns 4 cells. Lane l: row-select = l>>4, channel quad = (l&15)*4.
// One float4 load per lane per iteration covers 4 rows of one cell.
__global__ __launch_bounds__(1024) void lss_accum(
    const float* __restrict__ x,         // [NPRIME, 64]
    const unsigned* __restrict__ cnt,    // [NCELLS]
    const int* __restrict__ slots,       // [NCELLS, CAP]
    float* __restrict__ out)             // [4, 64, 30000]
{
    __shared__ float tile[64][65];
    int b    = blockIdx.y;
    int xy0  = blockIdx.x * 64;
    int t    = threadIdx.x;
    int wave = t >> 6;                   // 0..15
    int lane = t & 63;
    int rowsel = lane >> 4;              // 0..3  (which row of the quad)
    int chq    = (lane & 15) * 4;        // channel quad base

    int xyW = xy0 + wave * 4;            // this wave's 4 cells
    int n_[4];
    const int* sl_[4];
    #pragma unroll
    for (int q = 0; q < 4; ++q) {
        int xy = xyW + q;
        int cell = b * CELLS_PER_B + xy;
        int n = (xy < CELLS_PER_B) ? (int)cnt[cell] : 0;
        n_[q]  = n > CAP ? CAP : n;
        sl_[q] = slots + (size_t)cell * CAP;
    }

    float4 acc0 = {0,0,0,0}, acc1 = {0,0,0,0}, acc2 = {0,0,0,0}, acc3 = {0,0,0,0};
    int nmax = max(max(n_[0], n_[1]), max(n_[2], n_[3]));

    for (int i = 0; i < nmax; i += 4) {
        // per-cell uniform branch (n_ wave-uniform) -> no divergence, no
        // wasted issue for finished cells; tail lanes clamp to slot 0 (L2-hot)
        #define GATHER(Q, ACC)                                                    \
            if (i < n_[Q]) {                                                      \
                int jj = i + rowsel;                                              \
                int j  = jj < n_[Q] ? jj : 0;                                     \
                unsigned p = min((unsigned)sl_[Q][j], NPRIME - 1u);               \
                const float4 v = *reinterpret_cast<const float4*>(                \
                    x + (size_t)p * NCH + chq);                                   \
                if (jj < n_[Q]) { ACC.x += v.x; ACC.y += v.y;                     \
                                  ACC.z += v.z; ACC.w += v.w; }                   \
            }
        GATHER(0, acc0)
        GATHER(1, acc1)
        GATHER(2, acc2)
        GATHER(3, acc3)
        #undef GATHER
    }

    // merge the 4 row-groups: butterfly over lane^16, lane^32
    #define BFLY(ACC)                                                             \
        ACC.x += __shfl_xor(ACC.x, 16); ACC.y += __shfl_xor(ACC.y, 16);           \
        ACC.z += __shfl_xor(ACC.z, 16); ACC.w += __shfl_xor(ACC.w, 16);           \
        ACC.x += __shfl_xor(ACC.x, 32); ACC.y += __shfl_xor(ACC.y, 32);           \
        ACC.z += __shfl_xor(ACC.z, 32); ACC.w += __shfl_xor(ACC.w, 32);
    BFLY(acc0) BFLY(acc1) BFLY(acc2) BFLY(acc3)
    #undef BFLY

    if (lane < 16) {
        int c0 = lane * 4;
        *reinterpret_cast<float4*>(&tile[wave * 4 + 0][c0]) = acc0;
        *reinterpret_cast<float4*>(&tile[wave * 4 + 1][c0]) = acc1;
        *reinterpret_cast<float4*>(&tile[wave * 4 + 2][c0]) = acc2;
        *reinterpret_cast<float4*>(&tile[wave * 4 + 3][c0]) = acc3;
    }
    __syncthreads();

    // transposed write: thread t -> c = t>>4, xyl = (t&15)*4 (float4)
    int c   = t >> 4;                    // 0..63
    int xyl = (t & 15) * 4;
    int xy  = xy0 + xyl;
    if (xy + 3 < CELLS_PER_B) {          // 30000 % 4 == 0
        float4 w;
        w.x = tile[xyl + 0][c];
        w.y = tile[xyl + 1][c];
        w.z = tile[xyl + 2][c];
        w.w = tile[xyl + 3][c];
        *reinterpret_cast<float4*>(out + ((size_t)(b * NCH + c)) * CELLS_PER_B + xy) = w;
    }
}

// ---- fallback (small ws), validated v7 path ----
__global__ __launch_bounds__(256) void lss_bin(
    const float* __restrict__ geom, int* __restrict__ cell)
{
    int p = blockIdx.x * 256 + threadIdx.x;
    if (p >= NPRIME) return;
    cell[p] = compute_cell(geom[3 * p], geom[3 * p + 1], geom[3 * p + 2], p);
}

__global__ __launch_bounds__(256) void lss_scatter_direct(
    const float* __restrict__ x, const int* __restrict__ cell,
    float* __restrict__ out)
{
    int t = blockIdx.x * 256 + threadIdx.x;
    int p = t >> 4;
    if (p >= NPRIME) return;
    int c = cell[p];
    if (c < 0) return;
    int c4 = (t & 15) << 2;
    const float4 xv = *reinterpret_cast<const float4*>(x + (size_t)p * NCH + c4);
    int b  = c / CELLS_PER_B;
    int xy = c - b * CELLS_PER_B;
    float* o = out + ((size_t)(b * NCH + c4)) * CELLS_PER_B + xy;
    atomicAdd(o,                   xv.x);
    atomicAdd(o +     CELLS_PER_B, xv.y);
    atomicAdd(o + 2 * CELLS_PER_B, xv.z);
    atomicAdd(o + 3 * CELLS_PER_B, xv.w);
}

__global__ __launch_bounds__(256) void lss_fused(
    const float* __restrict__ geom, const float* __restrict__ x,
    float* __restrict__ out)
{
    int t = blockIdx.x * 256 + threadIdx.x;
    int p = t >> 4;
    if (p >= NPRIME) return;
    int c = compute_cell(geom[3 * p], geom[3 * p + 1], geom[3 * p + 2], p);
    if (c < 0) return;
    int b  = c / CELLS_PER_B;
    int xy = c - b * CELLS_PER_B;
    int c4 = (t & 15) << 2;
    const float4 xv = *reinterpret_cast<const float4*>(x + (size_t)p * NCH + c4);
    float* o = out + ((size_t)(b * NCH + c4)) * CELLS_PER_B + xy;
    atomicAdd(o,                   xv.x);
    atomicAdd(o +     CELLS_PER_B, xv.y);
    atomicAdd(o + 2 * CELLS_PER_B, xv.z);
    atomicAdd(o + 3 * CELLS_PER_B, xv.w);
}

extern "C" void kernel_launch(void* const* d_in, const int* in_sizes, int n_in,
                              void* d_out, int out_size, void* d_ws, size_t ws_size,
                              hipStream_t stream) {
    const float* geom = (const float*)d_in[0];
    const float* x    = (const float*)d_in[1];
    float* out = (float*)d_out;

    const int bin_blocks = (NPRIME + 255) / 256;

    if (ws_size >= CNT_BYTES + SLOT_BYTES) {
        unsigned* cnt = (unsigned*)d_ws;
        int* slots    = (int*)((char*)d_ws + CNT_BYTES);
        lss_zero<<<(NCELLS + 255) / 256, 256, 0, stream>>>(cnt);
        lss_bin_push<<<bin_blocks, 256, 0, stream>>>(geom, cnt, slots);
        dim3 agrid((CELLS_PER_B + 63) / 64, 4);      // 469 x 4
        lss_accum<<<agrid, 1024, 0, stream>>>(x, cnt, slots, out);
    } else if (ws_size >= CELL_BYTES) {
        int* cell = (int*)d_ws;
        hipMemsetAsync(d_out, 0, (size_t)out_size * sizeof(float), stream);
        lss_bin<<<bin_blocks, 256, 0, stream>>>(geom, cell);
        lss_scatter_direct<<<(NPRIME * 16 + 255) / 256, 256, 0, stream>>>(x, cell, out);
    } else {
        hipMemsetAsync(d_out, 0, (size_t)out_size * sizeof(float), stream);
        lss_fused<<<(NPRIME * 16 + 255) / 256, 256, 0, stream>>>(geom, x, out);
    }
}